// Round 3
// baseline (355.142 us; speedup 1.0000x reference)
//
#include <hip/hip_runtime.h>
#include <math.h>

#define NROWS  (1024 * 4096)       // 2^22 rows of 8 floats (32 B)
#define BLOCKS 4096
#define TPB    256
#define R      4                   // rows per thread: BLOCKS*TPB*R == NROWS
#define NW     (TPB / 64)

// d_ws uint32 layout (cache-line spread): [0]=c1 [32]=c2 [64]=c3 [96]=c4 [128]=ticket

__global__ __launch_bounds__(TPB) void penalty_main(
        const float* __restrict__ x,
        const float* __restrict__ min_,
        const float* __restrict__ scale_,
        unsigned int* __restrict__ ws,
        float* __restrict__ out) {
    const float min2 = min_[2], min3 = min_[3];
    const float sc2  = scale_[2], sc3 = scale_[3];

    const int tid  = threadIdx.x;
    const int lane = tid & 63;
    const int wave = tid >> 6;
    const unsigned T = BLOCKS * TPB;              // 2^20 threads
    const unsigned t = blockIdx.x * TPB + tid;    // first row for this thread

    // ---- dense full-row loads: row i = float4[2i] (cols0-3) + float4[2i+1] (cols4-7).
    // cols 2,3 live in lo.z/lo.w; hi is fetched only to keep the HBM stream dense.
    const float4* __restrict__ x4 = (const float4*)x;
    float4 lo[R], hi[R];
    #pragma unroll
    for (int r = 0; r < R; ++r) lo[r] = x4[2u * (t + (unsigned)r * T)];
    #pragma unroll
    for (int r = 0; r < R; ++r) hi[r] = x4[2u * (t + (unsigned)r * T) + 1u];

    // ---- per-row predicates (exact same arithmetic as reference) ----
    float a[R];
    unsigned c1 = 0, c2 = 0, c4 = 0;
    #pragma unroll
    for (int r = 0; r < R; ++r) {
        const float d = (lo[r].z - min2) / sc2;
        a[r] = (lo[r].w - min3) / sc3;
        c1 += !(d >= 0.0f && d <= 252.0f);
        c2 += (a[r] < 0.0f) || (a[r] > 22.0f);
        c4 += (a[r] != 22.0f);
    }

    // consume hi so the loads aren't eliminated: gaussian data is finite, so
    // dummy*0.0f == 0.0f always and this adds exactly 0 to c1.
    float dummy = 0.0f;
    #pragma unroll
    for (int r = 0; r < R; ++r) dummy += hi[r].x + hi[r].y + hi[r].z + hi[r].w;
    c1 += (dummy * 0.0f != 0.0f);

    // ---- cross-wave handoff of a[] (lane 0 of each wave publishes) ----
    __shared__ float sA[NW][R];
    if (lane == 0) {
        #pragma unroll
        for (int r = 0; r < R; ++r) sA[wave][r] = a[r];
    }
    __syncthreads();

    // tid==255: neighbor rows are in the next block -> R boundary loads
    float abound[R];
    if (tid == TPB - 1) {
        #pragma unroll
        for (int r = 0; r < R; ++r) {
            const unsigned j = t + (unsigned)r * T + 1u;
            abound[r] = (j < NROWS) ? (x[8u * j + 3u] - min3) / sc3 : 0.0f;
        }
    }

    // ---- transition penalty ----
    unsigned c3 = 0;
    #pragma unroll
    for (int r = 0; r < R; ++r) {
        float an = __shfl_down(a[r], 1);
        if (lane == 63) an = (wave < NW - 1) ? sA[wave + 1][r] : abound[r];
        const unsigned i = t + (unsigned)r * T;
        const float h = 0.5f * a[r];               // a even integer <=> h==floor(h)
        const bool cond = (h == floorf(h)) && (a[r] < 20.0f) && (i + 1u < NROWS);
        const bool invalid = (an != a[r] + 1.0f) && (an != 22.0f);
        c3 += (cond && invalid);
    }

    // ---- block reduction ----
    for (int off = 32; off > 0; off >>= 1) {
        c1 += __shfl_down(c1, off);
        c2 += __shfl_down(c2, off);
        c3 += __shfl_down(c3, off);
        c4 += __shfl_down(c4, off);
    }
    __shared__ unsigned int s[NW][4];
    if (lane == 0) { s[wave][0] = c1; s[wave][1] = c2; s[wave][2] = c3; s[wave][3] = c4; }
    __syncthreads();

    // ---- fused finalize: spread atomics + ticket, last block writes out ----
    if (tid == 0) {
        unsigned t1 = 0, t2 = 0, t3 = 0, t4 = 0;
        #pragma unroll
        for (int w = 0; w < NW; ++w) {
            t1 += s[w][0]; t2 += s[w][1]; t3 += s[w][2]; t4 += s[w][3];
        }
        atomicAdd(&ws[0],  t1);      // fire-and-forget (no return value used)
        atomicAdd(&ws[32], t2);
        atomicAdd(&ws[64], t3);
        atomicAdd(&ws[96], t4);
        __threadfence();             // order accum atomics before ticket
        const unsigned old = atomicAdd(&ws[128], 1u);
        if (old == BLOCKS - 1) {     // all other blocks' accums are at coherence point
            __threadfence();
            const unsigned f1 = atomicAdd(&ws[0],  0u);
            const unsigned f2 = atomicAdd(&ws[32], 0u);
            const unsigned f3 = atomicAdd(&ws[64], 0u);
            const unsigned f4 = atomicAdd(&ws[96], 0u);
            out[0] = (float)f1 + (float)f2 + (float)f3
                   + fabsf((float)f4 - 58.0f);
        }
    }
}

extern "C" void kernel_launch(void* const* d_in, const int* in_sizes, int n_in,
                              void* d_out, int out_size, void* d_ws, size_t ws_size,
                              hipStream_t stream) {
    const float* x  = (const float*)d_in[0];
    const float* mn = (const float*)d_in[1];
    const float* sc = (const float*)d_in[2];
    unsigned int* ws = (unsigned int*)d_ws;
    float* out = (float*)d_out;

    // zero accumulators + ticket (d_ws is 0xAA-poisoned before every launch)
    hipMemsetAsync(ws, 0, 129 * sizeof(unsigned int), stream);
    penalty_main<<<BLOCKS, TPB, 0, stream>>>(x, mn, sc, ws, out);
}

// Round 4
// 205.272 us; speedup vs baseline: 1.7301x; 1.7301x over previous
//
#include <hip/hip_runtime.h>
#include <math.h>

#define NROWS  (1024 * 4096)       // 2^22 rows of 8 floats
#define BLOCKS 1024
#define TPB    256
#define R      16                  // rows per thread: BLOCKS*TPB*R == NROWS
#define NW     (TPB / 64)

__global__ __launch_bounds__(TPB) void penalty_main(
        const float* __restrict__ x,
        const float* __restrict__ min_,
        const float* __restrict__ scale_,
        unsigned int* __restrict__ part) {
    const float min2 = min_[2], min3 = min_[3];
    const float sc2  = scale_[2], sc3 = scale_[3];

    const int tid  = threadIdx.x;
    const int lane = tid & 63;
    const int wave = tid >> 6;
    const unsigned T = BLOCKS * TPB;              // 2^18 threads
    const unsigned t = blockIdx.x * TPB + tid;    // first row for this thread

    // ---- phase 1: issue ALL R loads before any consumption ----
    float2 v[R];
    #pragma unroll
    for (int r = 0; r < R; ++r) {
        v[r] = *(const float2*)(x + 8u * (t + (unsigned)r * T) + 2u);  // cols 2,3
    }
    // Compiler barrier: forbid sinking loads into the consume loop.
    // R2's VGPR_Count=12 proved the compiler serialized load->use; this
    // keeps 16 vmem ops outstanding per thread.
    asm volatile("" ::: "memory");

    // ---- phase 2: per-row predicates ----
    float a[R];
    unsigned c1 = 0, c2 = 0, c4 = 0;
    #pragma unroll
    for (int r = 0; r < R; ++r) {
        const float d = (v[r].x - min2) / sc2;
        a[r] = (v[r].y - min3) / sc3;
        c1 += !(d >= 0.0f && d <= 252.0f);
        c2 += (a[r] < 0.0f) || (a[r] > 22.0f);
        c4 += (a[r] != 22.0f);
    }

    // ---- cross-wave handoff: lane 0 of each wave publishes its a[] ----
    __shared__ float sA[NW][R];
    if (lane == 0) {
        #pragma unroll
        for (int r = 0; r < R; ++r) sA[wave][r] = a[r];
    }
    __syncthreads();

    // tid==255: neighbor rows live in the next block -> R boundary loads
    float abound[R];
    if (tid == TPB - 1) {
        #pragma unroll
        for (int r = 0; r < R; ++r) {
            const unsigned j = t + (unsigned)r * T + 1u;
            abound[r] = (j < NROWS) ? (x[8u * j + 3u] - min3) / sc3 : 0.0f;
        }
    }

    // ---- transition penalty ----
    unsigned c3 = 0;
    #pragma unroll
    for (int r = 0; r < R; ++r) {
        float an = __shfl_down(a[r], 1);
        if (lane == 63) an = (wave < NW - 1) ? sA[wave + 1][r] : abound[r];
        const unsigned i = t + (unsigned)r * T;
        const bool cond = (fmodf(a[r], 2.0f) == 0.0f) && (a[r] < 20.0f)
                          && (i + 1u < NROWS);
        const bool invalid = (an != a[r] + 1.0f) && (an != 22.0f);
        c3 += (cond && invalid);
    }

    // ---- block reduction, plain stores (NO atomics, NO fences) ----
    for (int off = 32; off > 0; off >>= 1) {
        c1 += __shfl_down(c1, off);
        c2 += __shfl_down(c2, off);
        c3 += __shfl_down(c3, off);
        c4 += __shfl_down(c4, off);
    }
    __shared__ unsigned int s[NW][4];
    if (lane == 0) { s[wave][0] = c1; s[wave][1] = c2; s[wave][2] = c3; s[wave][3] = c4; }
    __syncthreads();
    if (tid == 0) {
        unsigned t1 = 0, t2 = 0, t3 = 0, t4 = 0;
        #pragma unroll
        for (int w = 0; w < NW; ++w) {
            t1 += s[w][0]; t2 += s[w][1]; t3 += s[w][2]; t4 += s[w][3];
        }
        unsigned int* p = part + 4u * blockIdx.x;
        p[0] = t1; p[1] = t2; p[2] = t3; p[3] = t4;
    }
}

__global__ __launch_bounds__(TPB) void finalize(
        const unsigned int* __restrict__ part, float* __restrict__ out) {
    const int tid = threadIdx.x;
    unsigned c1 = 0, c2 = 0, c3 = 0, c4 = 0;
    for (int b = tid; b < BLOCKS; b += TPB) {
        const unsigned int* p = part + 4 * b;
        c1 += p[0]; c2 += p[1]; c3 += p[2]; c4 += p[3];
    }
    for (int off = 32; off > 0; off >>= 1) {
        c1 += __shfl_down(c1, off);
        c2 += __shfl_down(c2, off);
        c3 += __shfl_down(c3, off);
        c4 += __shfl_down(c4, off);
    }
    __shared__ unsigned int s[NW][4];
    const int lane = tid & 63, wave = tid >> 6;
    if (lane == 0) { s[wave][0] = c1; s[wave][1] = c2; s[wave][2] = c3; s[wave][3] = c4; }
    __syncthreads();
    if (tid == 0) {
        unsigned t1 = 0, t2 = 0, t3 = 0, t4 = 0;
        #pragma unroll
        for (int w = 0; w < NW; ++w) {
            t1 += s[w][0]; t2 += s[w][1]; t3 += s[w][2]; t4 += s[w][3];
        }
        out[0] = (float)t1 + (float)t2 + (float)t3
               + fabsf((float)t4 - 58.0f);
    }
}

extern "C" void kernel_launch(void* const* d_in, const int* in_sizes, int n_in,
                              void* d_out, int out_size, void* d_ws, size_t ws_size,
                              hipStream_t stream) {
    const float* x  = (const float*)d_in[0];
    const float* mn = (const float*)d_in[1];
    const float* sc = (const float*)d_in[2];
    unsigned int* part = (unsigned int*)d_ws;      // BLOCKS*4 uints = 16 KB
    float* out = (float*)d_out;

    penalty_main<<<BLOCKS, TPB, 0, stream>>>(x, mn, sc, part);
    finalize<<<1, TPB, 0, stream>>>(part, out);
}